// Round 4
// baseline (322.060 us; speedup 1.0000x reference)
//
#include <hip/hip_runtime.h>

// B=8, S=1024, D=1024, H=16, P=64. FP32 I/O, bf16 MFMA compute.
// convert W -> bf16 | QKV GEMM direct from fp32 acts (in-register RNE
// conversion, m97 structure) | MFMA batch-softmax attention | final GEMM
// + sigmoid. 4 dispatches total.

using short8   = __attribute__((ext_vector_type(8))) short;    // 8 bf16
using floatx4  = __attribute__((ext_vector_type(4))) float;    // MFMA acc 16x16
using floatx16 = __attribute__((ext_vector_type(16))) float;   // MFMA acc 32x32

__device__ __forceinline__ float bf2f(unsigned short u) {
    return __uint_as_float(((unsigned)u) << 16);
}
__device__ __forceinline__ unsigned short f2bf(float f) {   // RNE
    unsigned u = __float_as_uint(f);
    u += 0x7fffu + ((u >> 16) & 1u);
    return (unsigned short)(u >> 16);
}
// two fp32 -> packed bf16 pair (truncation) in one v_perm: lo16=f0, hi16=f1
__device__ __forceinline__ unsigned pack_trunc(float f0, float f1) {
    return __builtin_amdgcn_perm(__float_as_uint(f1), __float_as_uint(f0), 0x07060302u);
}
// RNE pair pack (matches the separate-convert pass numerics exactly)
__device__ __forceinline__ unsigned pack_rne(float f0, float f1) {
    return (unsigned)f2bf(f0) | ((unsigned)f2bf(f1) << 16);
}
__device__ __forceinline__ void async_ld16(const void* g, void* l) {
    __builtin_amdgcn_global_load_lds(
        (const __attribute__((address_space(1))) unsigned int*)g,
        (__attribute__((address_space(3))) unsigned int*)l, 16, 0, 0);
}

// ---------------------------------------------------------------------------
// fp32 -> bf16 (RNE) converter for weights (4 MB each, 4 matrices)
// ---------------------------------------------------------------------------
__device__ __forceinline__ void conv8(const float* src, unsigned short* d, size_t i) {
    float4 a = *(const float4*)(src + i);
    float4 b = *(const float4*)(src + i + 4);
    uint4 o;
    o.x = pack_rne(a.x, a.y);
    o.y = pack_rne(a.z, a.w);
    o.z = pack_rne(b.x, b.y);
    o.w = pack_rne(b.z, b.w);
    *(uint4*)(d + i) = o;
}

__global__ __launch_bounds__(256) void convert_weights(
    const float* __restrict__ w0, const float* __restrict__ w1,
    const float* __restrict__ w2, const float* __restrict__ w3,
    unsigned short* __restrict__ dst)
{
    const float* srcs[4] = {w0, w1, w2, w3};
    conv8(srcs[blockIdx.y], dst + (size_t)blockIdx.y * (1024u * 1024u),
          ((size_t)blockIdx.x * 256 + threadIdx.x) * 8);
}

// ---------------------------------------------------------------------------
// 128x128 GEMM (m97 structure): C = A.W^T + bias. BK=32, 4 waves 2x2.
// AF32=true: A is fp32, staged raw and converted to bf16 (RNE) during the
// fragment read — fuses the activation-convert pass into the GEMM.
// grid.z picks among 3 problem tuples (QKV fusion).
// ---------------------------------------------------------------------------
template<bool AF32, bool SIG>
__global__ __launch_bounds__(256) void gemm128(
    const void* __restrict__ A0, const void* __restrict__ A1, const void* __restrict__ A2,
    const unsigned short* __restrict__ W0, const unsigned short* __restrict__ W1,
    const unsigned short* __restrict__ W2,
    const float* __restrict__ b0, const float* __restrict__ b1, const float* __restrict__ b2,
    void* __restrict__ C0, void* __restrict__ C1, void* __restrict__ C2)
{
    const int z = blockIdx.z;
    const void* Ap = (z == 0) ? A0 : (z == 1) ? A1 : A2;
    const unsigned short* W = (z == 0) ? W0 : (z == 1) ? W1 : W2;
    const float* bias = (z == 0) ? b0 : (z == 1) ? b1 : b2;
    void* Cp = (z == 0) ? C0 : (z == 1) ? C1 : C2;

    constexpr int Kd = 1024, Nd = 1024;
    const int t = threadIdx.x;
    const int w = t >> 6, lane = t & 63;
    const int l15 = lane & 15, quad = lane >> 4;
    const int blockM = blockIdx.x * 128;
    const int blockN = blockIdx.y * 128;
    const int wy = w >> 1, wx = w & 1;

    __shared__ unsigned short Bs[128 * 32];
    constexpr int ABYTES = AF32 ? (128 * 32 * 4) : (128 * 32 * 2);
    __shared__ __align__(16) unsigned char AsRaw[ABYTES];
    float* AsF = (float*)AsRaw;
    unsigned short* AsB = (unsigned short*)AsRaw;

    const int br  = lane >> 2;
    const int bg  = (lane & 3) ^ (br & 3);
    const unsigned short* Bsrc0 = W + (size_t)(blockN + w * 32 + br) * Kd + bg * 8;
    const unsigned short* Bsrc1 = Bsrc0 + (size_t)16 * Kd;
    unsigned short* Bdst0 = &Bs[(w * 2 + 0) * 512];
    unsigned short* Bdst1 = &Bs[(w * 2 + 1) * 512];

    const int ar = lane >> 3;
    const int ag = (lane & 7) ^ (ar & 7);
    const float* AsrcF[4];
    float* AdstF[4];
    const unsigned short* AsrcB0 = nullptr; const unsigned short* AsrcB1 = nullptr;
    unsigned short* AdstB0 = nullptr; unsigned short* AdstB1 = nullptr;
    if (AF32) {
        #pragma unroll
        for (int j = 0; j < 4; ++j) {
            AsrcF[j] = (const float*)Ap + (size_t)(blockM + w * 32 + j * 8 + ar) * Kd + ag * 4;
            AdstF[j] = AsF + (w * 4 + j) * 256;
        }
    } else {
        AsrcB0 = (const unsigned short*)Ap + (size_t)(blockM + w * 32 + br) * Kd + bg * 8;
        AsrcB1 = AsrcB0 + (size_t)16 * Kd;
        AdstB0 = &AsB[(w * 2 + 0) * 512];
        AdstB1 = &AsB[(w * 2 + 1) * 512];
    }

    floatx4 acc[4][4] = {};

    for (int k0 = 0; k0 < Kd; k0 += 32) {
        if (AF32) {
            #pragma unroll
            for (int j = 0; j < 4; ++j) async_ld16(AsrcF[j] + k0, AdstF[j]);
        } else {
            async_ld16(AsrcB0 + k0, AdstB0);
            async_ld16(AsrcB1 + k0, AdstB1);
        }
        async_ld16(Bsrc0 + k0, Bdst0);
        async_ld16(Bsrc1 + k0, Bdst1);
        __syncthreads();

        short8 af[4], bfr[4];
        #pragma unroll
        for (int mt = 0; mt < 4; ++mt) {
            const int row = wy * 64 + mt * 16 + l15;
            if (AF32) {
                const int r7 = l15 & 7;
                const float* ap = AsF + row * 32;
                float4 lo = *(const float4*)(ap + (((quad * 2 + 0) ^ r7) * 4));
                float4 hi = *(const float4*)(ap + (((quad * 2 + 1) ^ r7) * 4));
                union { unsigned u[4]; short8 s; } cv;
                cv.u[0] = pack_rne(lo.x, lo.y);
                cv.u[1] = pack_rne(lo.z, lo.w);
                cv.u[2] = pack_rne(hi.x, hi.y);
                cv.u[3] = pack_rne(hi.z, hi.w);
                af[mt] = cv.s;
            } else {
                af[mt] = *(const short8*)&AsB[row * 32 + (quad ^ (l15 & 3)) * 8];
            }
        }
        #pragma unroll
        for (int nt = 0; nt < 4; ++nt) {
            const int row = wx * 64 + nt * 16 + l15;
            bfr[nt] = *(const short8*)&Bs[row * 32 + (quad ^ (l15 & 3)) * 8];
        }
        #pragma unroll
        for (int mt = 0; mt < 4; ++mt)
            #pragma unroll
            for (int nt = 0; nt < 4; ++nt)
                acc[mt][nt] = __builtin_amdgcn_mfma_f32_16x16x32_bf16(af[mt], bfr[nt], acc[mt][nt], 0, 0, 0);
        __syncthreads();
    }

    #pragma unroll
    for (int nt = 0; nt < 4; ++nt) {
        const int col = blockN + wx * 64 + nt * 16 + l15;
        const float bv = bias[col];
        #pragma unroll
        for (int mt = 0; mt < 4; ++mt) {
            const int row = blockM + wy * 64 + mt * 16 + quad * 4;
            #pragma unroll
            for (int r = 0; r < 4; ++r) {
                float v = acc[mt][nt][r] + bv;
                if (SIG) {
                    v = 1.0f / (1.0f + __expf(-v));
                    ((float*)Cp)[(size_t)(row + r) * Nd + col] = v;
                } else {
                    ((unsigned short*)Cp)[(size_t)(row + r) * Nd + col] = f2bf(v);
                }
            }
        }
    }
}

// ---------------------------------------------------------------------------
// MFMA attention. grid = (S=1024, 2 p-halves), block = 512 (wave = b).
// Per (b,s): S[p][q] = sum_h Q[p][h] K[q][h] / 8; softmax over b (8 waves,
// via LDS); out[p][h] = sum_q attn[p][q] V[q][h].
//
// Stages (LDS, shorts; total 27648 = 55.3 KB):
//   Vt [8][16][72] @0      : V^T (h-major, q-contig) for PV B-frags
//   Kl [8][64][16] @9216   : K (q-major, h-contig) for score A-frags
//   Ql [8][32][16] @17408  : Q half (p-major, h-contig) for score B-frags
//   Sexp[8][32][72] @9216  : exp(scores) [p][q], overlays Kl+Ql after scores
//   Ol [8][16][36] @9216+b*2304 : out [h][p], overlays own Sexp plane
// ---------------------------------------------------------------------------
__global__ __launch_bounds__(512) void attn_mfma(
    const unsigned short* __restrict__ Q,
    const unsigned short* __restrict__ Kt,
    const unsigned short* __restrict__ Vt,
    unsigned short* __restrict__ O2)
{
    constexpr int VOFF = 0;        // shorts
    constexpr int UOFF = 9216;     // shorts (16B-aligned: 18432 B)
    constexpr int QOFF = UOFF + 8192;
    __shared__ __align__(16) unsigned short lds[UOFF + 18432];

    const int s  = blockIdx.x;
    const int ph = blockIdx.y;
    const int t  = threadIdx.x;
    const int w  = t >> 6;          // wave = b
    const int l  = t & 63;
    const int l15 = l & 15, l31 = l & 31, half = l >> 5, quad = l >> 4;

    const size_t gb = ((size_t)w * 1024 + s) * 1024;  // shorts

    // ---- load phase ----
    {
        const unsigned* vg = (const unsigned*)(Vt + gb);
        unsigned* vd = (unsigned*)lds;            // Vt dword base
        #pragma unroll
        for (int it = 0; it < 8; ++it) {
            const int h = it * 2 + half;
            vd[w * 576 + h * 36 + l31] = vg[h * 32 + l31];
        }
        const unsigned short* kg = Kt + gb;
        unsigned* kd = (unsigned*)(lds + UOFF);
        #pragma unroll
        for (int h2 = 0; h2 < 8; ++h2) {
            unsigned klo = kg[(2 * h2) * 64 + l];
            unsigned khi = kg[(2 * h2 + 1) * 64 + l];
            kd[w * 512 + l * 8 + h2] = klo | (khi << 16);
        }
        const unsigned short* qg = Q + gb + ph * 32;
        unsigned* qd = (unsigned*)(lds + QOFF);
        #pragma unroll
        for (int it = 0; it < 4; ++it) {
            const int h = it * 4 + half * 2;
            unsigned qlo = qg[h * 64 + l31];
            unsigned qhi = qg[(h + 1) * 64 + l31];
            qd[w * 256 + l31 * 8 + it * 2 + half] = qlo | (qhi << 16);
        }
    }
    __syncthreads();

    // ---- scores: A=K (m=q), B=Q (n=p), K=16=h ----
    floatx16 sc[2];
    {
        short8 qf = *(const short8*)&lds[QOFF + w * 512 + l31 * 16 + half * 8];
        short8 kf0 = *(const short8*)&lds[UOFF + w * 1024 + l31 * 16 + half * 8];
        short8 kf1 = *(const short8*)&lds[UOFF + w * 1024 + (32 + l31) * 16 + half * 8];
        floatx16 z = {};
        sc[0] = __builtin_amdgcn_mfma_f32_32x32x16_bf16(kf0, qf, z, 0, 0, 0);
        sc[1] = __builtin_amdgcn_mfma_f32_32x32x16_bf16(kf1, qf, z, 0, 0, 0);
    }
    __syncthreads();   // K/Q region dead -> reuse as Sexp

    // ---- exp + Sexp[p][q] writes (p = l31, q from C layout) ----
    {
        unsigned short* sx = lds + UOFF + w * 2304 + l31 * 72;
        #pragma unroll
        for (int nt = 0; nt < 2; ++nt) {
            #pragma unroll
            for (int rg = 0; rg < 4; ++rg) {
                float e0 = __expf(sc[nt][4 * rg + 0] * 0.125f);
                float e1 = __expf(sc[nt][4 * rg + 1] * 0.125f);
                float e2 = __expf(sc[nt][4 * rg + 2] * 0.125f);
                float e3 = __expf(sc[nt][4 * rg + 3] * 0.125f);
                uint2 pk = { pack_trunc(e0, e1), pack_trunc(e2, e3) };
                const int q0 = nt * 32 + rg * 8 + half * 4;
                *(uint2*)&sx[q0] = pk;
            }
        }
    }
    __syncthreads();

    // ---- batch-softmax denominators: thread owns (p=t&31, q0=(t>>5)*4) ----
    {
        const int p  = t & 31;
        const int q0 = (t >> 5) * 4;
        unsigned short* base = lds + UOFF + p * 72 + q0;
        float fv[8][4];
        float den0 = 0.f, den1 = 0.f, den2 = 0.f, den3 = 0.f;
        #pragma unroll
        for (int b = 0; b < 8; ++b) {
            uint2 v = *(const uint2*)&base[b * 2304];
            fv[b][0] = bf2f((unsigned short)(v.x & 0xffff));
            fv[b][1] = bf2f((unsigned short)(v.x >> 16));
            fv[b][2] = bf2f((unsigned short)(v.y & 0xffff));
            fv[b][3] = bf2f((unsigned short)(v.y >> 16));
            den0 += fv[b][0]; den1 += fv[b][1]; den2 += fv[b][2]; den3 += fv[b][3];
        }
        const float r0 = __builtin_amdgcn_rcpf(den0);
        const float r1 = __builtin_amdgcn_rcpf(den1);
        const float r2 = __builtin_amdgcn_rcpf(den2);
        const float r3 = __builtin_amdgcn_rcpf(den3);
        #pragma unroll
        for (int b = 0; b < 8; ++b) {
            uint2 pk = { pack_trunc(fv[b][0] * r0, fv[b][1] * r1),
                         pack_trunc(fv[b][2] * r2, fv[b][3] * r3) };
            *(uint2*)&base[b * 2304] = pk;
        }
    }
    __syncthreads();

    // ---- PV: A=weights[p][q], B=Vt[h][q]; out[p][h] ----
    floatx4 o[2] = {};
    #pragma unroll
    for (int qc = 0; qc < 2; ++qc) {
        short8 vf = *(const short8*)&lds[VOFF + w * 1152 + l15 * 72 + qc * 32 + quad * 8];
        #pragma unroll
        for (int mt = 0; mt < 2; ++mt) {
            short8 wf = *(const short8*)&lds[UOFF + w * 2304 + (mt * 16 + l15) * 72 + qc * 32 + quad * 8];
            o[mt] = __builtin_amdgcn_mfma_f32_16x16x32_bf16(wf, vf, o[mt], 0, 0, 0);
        }
    }
    {
        unsigned short* ol = lds + UOFF + w * 2304 + l15 * 36;
        #pragma unroll
        for (int mt = 0; mt < 2; ++mt) {
            uint2 pk = { pack_trunc(o[mt][0], o[mt][1]), pack_trunc(o[mt][2], o[mt][3]) };
            *(uint2*)&ol[mt * 16 + quad * 4] = pk;
        }
    }
    __syncthreads();

    // ---- coalesced store: per wave (b), 256 dwords ----
    {
        unsigned* outdw = (unsigned*)O2;
        const unsigned* ol = (const unsigned*)(lds + UOFF + w * 2304);
        const size_t gdw = ((size_t)w * 1024 + s) * 512 + ph * 16;
        #pragma unroll
        for (int i = 0; i < 4; ++i) {
            const int d = i * 64 + l;
            const int h = d >> 4, pq = d & 15;
            outdw[gdw + h * 32 + pq] = ol[h * 18 + pq];
        }
    }
}

// ---------------------------------------------------------------------------
extern "C" void kernel_launch(void* const* d_in, const int* in_sizes, int n_in,
                              void* d_out, int out_size, void* d_ws, size_t ws_size,
                              hipStream_t stream) {
    const float* query = (const float*)d_in[0];
    const float* key_  = (const float*)d_in[1];
    const float* value = (const float*)d_in[2];
    const float* Wq = (const float*)d_in[3];
    const float* bq = (const float*)d_in[4];
    const float* Wk = (const float*)d_in[5];
    const float* bk = (const float*)d_in[6];
    const float* Wv = (const float*)d_in[7];
    const float* bv = (const float*)d_in[8];
    const float* Wo = (const float*)d_in[9];
    const float* bo = (const float*)d_in[10];

    const size_t WN = (size_t)1024 * 1024;
    const size_t MN = (size_t)8192 * 1024;

    unsigned short* Wbf = (unsigned short*)d_ws;
    unsigned short* Wq_bf = Wbf;
    unsigned short* Wk_bf = Wbf + WN;
    unsigned short* Wv_bf = Wbf + 2 * WN;
    unsigned short* Wo_bf = Wbf + 3 * WN;

    convert_weights<<<dim3(512, 4), dim3(256), 0, stream>>>(Wq, Wk, Wv, Wo, Wbf);

    unsigned short* Qb = Wbf + 4 * WN;
    unsigned short* Kb = Qb + MN;
    unsigned short* Vb = Kb + MN;

    // QKV GEMM directly from fp32 activations (fused convert, RNE)
    gemm128<true, false><<<dim3(64, 8, 3), dim3(256), 0, stream>>>(
        query, key_, value, Wq_bf, Wk_bf, Wv_bf, bq, bk, bv, Qb, Kb, Vb);

    unsigned short* O2 = Qb;   // alias (safe, see attn_mfma)
    attn_mfma<<<dim3(1024, 2), dim3(512), 0, stream>>>(Qb, Kb, Vb, O2);

    gemm128<false, true><<<dim3(64, 8, 1), dim3(256), 0, stream>>>(
        O2, O2, O2, Wo_bf, Wo_bf, Wo_bf, bo, bo, bo, d_out, d_out, d_out);
}

// Round 5
// 281.576 us; speedup vs baseline: 1.1438x; 1.1438x over previous
//
#include <hip/hip_runtime.h>

// B=8, S=1024, D=1024, H=16, P=64. FP32 I/O, bf16 MFMA compute.
// convert W+acts -> bf16 | 8-phase pipelined 256x256 QKV GEMM | MFMA
// batch-softmax attention | 8-phase final GEMM + sigmoid.

using short8   = __attribute__((ext_vector_type(8))) short;    // 8 bf16
using floatx4  = __attribute__((ext_vector_type(4))) float;    // MFMA acc 16x16
using floatx16 = __attribute__((ext_vector_type(16))) float;   // MFMA acc 32x32

__device__ __forceinline__ float bf2f(unsigned short u) {
    return __uint_as_float(((unsigned)u) << 16);
}
__device__ __forceinline__ unsigned short f2bf(float f) {   // RNE
    unsigned u = __float_as_uint(f);
    u += 0x7fffu + ((u >> 16) & 1u);
    return (unsigned short)(u >> 16);
}
__device__ __forceinline__ unsigned pack_trunc(float f0, float f1) {
    return __builtin_amdgcn_perm(__float_as_uint(f1), __float_as_uint(f0), 0x07060302u);
}
__device__ __forceinline__ unsigned pack_rne(float f0, float f1) {
    return (unsigned)f2bf(f0) | ((unsigned)f2bf(f1) << 16);
}
__device__ __forceinline__ void async_ld16(const void* g, void* l) {
    __builtin_amdgcn_global_load_lds(
        (const __attribute__((address_space(1))) unsigned int*)g,
        (__attribute__((address_space(3))) unsigned int*)l, 16, 0, 0);
}
// Inline-asm LDS read: opaque to the compiler's waitcnt pass (no forced
// vmcnt(0) drain vs in-flight global_load_lds). Ordering is manual.
__device__ __forceinline__ short8 lds_read_b128(unsigned addr) {
    short8 r;
    asm volatile("ds_read_b128 %0, %1" : "=v"(r) : "v"(addr));
    return r;
}

// ---------------------------------------------------------------------------
// fp32 -> bf16 (RNE) converters
// ---------------------------------------------------------------------------
__device__ __forceinline__ void conv8(const float* src, unsigned short* d, size_t i) {
    float4 a = *(const float4*)(src + i);
    float4 b = *(const float4*)(src + i + 4);
    uint4 o;
    o.x = pack_rne(a.x, a.y);
    o.y = pack_rne(a.z, a.w);
    o.z = pack_rne(b.x, b.y);
    o.w = pack_rne(b.z, b.w);
    *(uint4*)(d + i) = o;
}

__global__ __launch_bounds__(256) void convert_weights(
    const float* __restrict__ w0, const float* __restrict__ w1,
    const float* __restrict__ w2, const float* __restrict__ w3,
    unsigned short* __restrict__ dst)
{
    const float* srcs[4] = {w0, w1, w2, w3};
    conv8(srcs[blockIdx.y], dst + (size_t)blockIdx.y * (1024u * 1024u),
          ((size_t)blockIdx.x * 256 + threadIdx.x) * 8);
}

__global__ __launch_bounds__(256) void convert_acts(
    const float* __restrict__ a0, const float* __restrict__ a1,
    const float* __restrict__ a2, unsigned short* __restrict__ dst)
{
    const float* srcs[3] = {a0, a1, a2};
    conv8(srcs[blockIdx.y], dst + (size_t)blockIdx.y * ((size_t)8192 * 1024),
          ((size_t)blockIdx.x * 256 + threadIdx.x) * 8);
}

// ---------------------------------------------------------------------------
// 128x128 GEMM (m97 structure) — small-workspace fallback only.
// ---------------------------------------------------------------------------
template<bool AF32, bool SIG>
__global__ __launch_bounds__(256) void gemm128(
    const void* __restrict__ A0, const void* __restrict__ A1, const void* __restrict__ A2,
    const unsigned short* __restrict__ W0, const unsigned short* __restrict__ W1,
    const unsigned short* __restrict__ W2,
    const float* __restrict__ b0, const float* __restrict__ b1, const float* __restrict__ b2,
    void* __restrict__ C0, void* __restrict__ C1, void* __restrict__ C2)
{
    const int z = blockIdx.z;
    const void* Ap = (z == 0) ? A0 : (z == 1) ? A1 : A2;
    const unsigned short* W = (z == 0) ? W0 : (z == 1) ? W1 : W2;
    const float* bias = (z == 0) ? b0 : (z == 1) ? b1 : b2;
    void* Cp = (z == 0) ? C0 : (z == 1) ? C1 : C2;

    constexpr int Kd = 1024, Nd = 1024;
    const int t = threadIdx.x;
    const int w = t >> 6, lane = t & 63;
    const int l15 = lane & 15, quad = lane >> 4;
    const int blockM = blockIdx.x * 128;
    const int blockN = blockIdx.y * 128;
    const int wy = w >> 1, wx = w & 1;

    __shared__ unsigned short Bs[128 * 32];
    constexpr int ABYTES = AF32 ? (128 * 32 * 4) : (128 * 32 * 2);
    __shared__ __align__(16) unsigned char AsRaw[ABYTES];
    float* AsF = (float*)AsRaw;
    unsigned short* AsB = (unsigned short*)AsRaw;

    const int br  = lane >> 2;
    const int bg  = (lane & 3) ^ (br & 3);
    const unsigned short* Bsrc0 = W + (size_t)(blockN + w * 32 + br) * Kd + bg * 8;
    const unsigned short* Bsrc1 = Bsrc0 + (size_t)16 * Kd;
    unsigned short* Bdst0 = &Bs[(w * 2 + 0) * 512];
    unsigned short* Bdst1 = &Bs[(w * 2 + 1) * 512];

    const int ar = lane >> 3;
    const int ag = (lane & 7) ^ (ar & 7);
    const float* AsrcF[4];
    float* AdstF[4];
    const unsigned short* AsrcB0 = nullptr; const unsigned short* AsrcB1 = nullptr;
    unsigned short* AdstB0 = nullptr; unsigned short* AdstB1 = nullptr;
    if (AF32) {
        #pragma unroll
        for (int j = 0; j < 4; ++j) {
            AsrcF[j] = (const float*)Ap + (size_t)(blockM + w * 32 + j * 8 + ar) * Kd + ag * 4;
            AdstF[j] = AsF + (w * 4 + j) * 256;
        }
    } else {
        AsrcB0 = (const unsigned short*)Ap + (size_t)(blockM + w * 32 + br) * Kd + bg * 8;
        AsrcB1 = AsrcB0 + (size_t)16 * Kd;
        AdstB0 = &AsB[(w * 2 + 0) * 512];
        AdstB1 = &AsB[(w * 2 + 1) * 512];
    }

    floatx4 acc[4][4] = {};

    for (int k0 = 0; k0 < Kd; k0 += 32) {
        if (AF32) {
            #pragma unroll
            for (int j = 0; j < 4; ++j) async_ld16(AsrcF[j] + k0, AdstF[j]);
        } else {
            async_ld16(AsrcB0 + k0, AdstB0);
            async_ld16(AsrcB1 + k0, AdstB1);
        }
        async_ld16(Bsrc0 + k0, Bdst0);
        async_ld16(Bsrc1 + k0, Bdst1);
        __syncthreads();

        short8 af[4], bfr[4];
        #pragma unroll
        for (int mt = 0; mt < 4; ++mt) {
            const int row = wy * 64 + mt * 16 + l15;
            if (AF32) {
                const int r7 = l15 & 7;
                const float* ap = AsF + row * 32;
                float4 lo = *(const float4*)(ap + (((quad * 2 + 0) ^ r7) * 4));
                float4 hi = *(const float4*)(ap + (((quad * 2 + 1) ^ r7) * 4));
                union { unsigned u[4]; short8 s; } cv;
                cv.u[0] = pack_rne(lo.x, lo.y);
                cv.u[1] = pack_rne(lo.z, lo.w);
                cv.u[2] = pack_rne(hi.x, hi.y);
                cv.u[3] = pack_rne(hi.z, hi.w);
                af[mt] = cv.s;
            } else {
                af[mt] = *(const short8*)&AsB[row * 32 + (quad ^ (l15 & 3)) * 8];
            }
        }
        #pragma unroll
        for (int nt = 0; nt < 4; ++nt) {
            const int row = wx * 64 + nt * 16 + l15;
            bfr[nt] = *(const short8*)&Bs[row * 32 + (quad ^ (l15 & 3)) * 8];
        }
        #pragma unroll
        for (int mt = 0; mt < 4; ++mt)
            #pragma unroll
            for (int nt = 0; nt < 4; ++nt)
                acc[mt][nt] = __builtin_amdgcn_mfma_f32_16x16x32_bf16(af[mt], bfr[nt], acc[mt][nt], 0, 0, 0);
        __syncthreads();
    }

    #pragma unroll
    for (int nt = 0; nt < 4; ++nt) {
        const int col = blockN + wx * 64 + nt * 16 + l15;
        const float bv = bias[col];
        #pragma unroll
        for (int mt = 0; mt < 4; ++mt) {
            const int row = blockM + wy * 64 + mt * 16 + quad * 4;
            #pragma unroll
            for (int r = 0; r < 4; ++r) {
                float v = acc[mt][nt][r] + bv;
                if (SIG) {
                    v = 1.0f / (1.0f + __expf(-v));
                    ((float*)Cp)[(size_t)(row + r) * Nd + col] = v;
                } else {
                    ((unsigned short*)Cp)[(size_t)(row + r) * Nd + col] = f2bf(v);
                }
            }
        }
    }
}

// ---------------------------------------------------------------------------
// gemm8p: 8-phase pipelined 256x256 GEMM (m201-class schedule, re-derived).
// C = A.W^T + bias; A,W bf16 row-major [.][1024]. K-tile 64 split into two
// 32-k half-regions per matrix. 512 thr = 8 waves (2M x 4N), wave tile
// 128x64, mfma_32x32x16, acc[4][2] floatx16.
//
// LDS (128 KiB) = 8 regions of 16 KB: A: buf*32768 + kh*16384 (bytes
// 0..64K); B: +65536. Region = 256 rows x 32 k; row = 64 B = 4 granules of
// 16 B, stored at slot = g ^ ((row>>1)&3)  (read-side proven conflict-free:
// 8 bank-quads fully covered). global_load_lds writes the region LINEARLY
// (wave-uniform dest + lane*16); the INVERSE permutation is applied to the
// per-lane global source address (both-sides-or-neither).
//
// Steady iteration i (tiles T=2i in buf0, T+1 in buf1), 8 phases, each:
//   [ds_read frags][stage 1 half][lgkmcnt(0)+schedbar][8 MFMA][vm?][barrier]
// ph1: rd buf0.kh0 (A-Mh0 + B)   stage (T+1).A.kh1 -> [A,1,1]
// ph2: rd buf0.kh0 (A-Mh1)      stage (T+2).B.kh0 -> [B,0,0]  VM10
// ph3: rd buf0.kh1 (A-Mh0 + B)   stage (T+2).A.kh0 -> [A,0,0]
// ph4: rd buf0.kh1 (A-Mh1)      stage (T+2).B.kh1 -> [B,0,1]  VM10
// ph5: rd buf1.kh0 (A-Mh0 + B)   stage (T+2).A.kh1 -> [A,0,1]
// ph6: rd buf1.kh0 (A-Mh1)      stage (T+3).B.kh0 -> [B,1,0]  VM10
// ph7: rd buf1.kh1 (A-Mh0 + B)   stage (T+3).A.kh0 -> [A,1,0]
// ph8: rd buf1.kh1 (A-Mh1)      stage (T+3).B.kh1 -> [B,1,1]  VM10
// Region-safety ledger: every region's stage is >=1 barrier after its last
// read ([B,0,0]: rd ph1/st ph2; [A,0,0]: rd ph1,2/st ph3; [B,0,1]: rd ph3/
// st ph4; [A,0,1]: rd ph3,4/st ph5; [B,1,0]: rd ph5/st ph6; [A,1,0]: rd
// ph5,6/st ph7; [B,1,1]: rd ph7/st ph8; [A,1,1]: rd ph7,8/st next-ph1).
// vmcnt(10) at end of even phases retires exactly the 2 halves (4 loads)
// the next odd phase reads (5 halves = 10 loads stay in flight); the
// following barrier gives cross-wave visibility. Prologue stages 7 halves
// (14 loads) + VM10 + barrier; iter0..6 steady; iter7 drains VM8/VM4/VM0.
// ---------------------------------------------------------------------------
#define VMW10 do { asm volatile("s_waitcnt vmcnt(10)" ::: "memory"); } while (0)
#define VMW8  do { asm volatile("s_waitcnt vmcnt(8)"  ::: "memory"); } while (0)
#define VMW4  do { asm volatile("s_waitcnt vmcnt(4)"  ::: "memory"); } while (0)
#define VMW0  do { asm volatile("s_waitcnt vmcnt(0)"  ::: "memory"); } while (0)
#define LGKM0 do { asm volatile("s_waitcnt lgkmcnt(0)" ::: "memory"); \
                   __builtin_amdgcn_sched_barrier(0); } while (0)
#define BARRIER __builtin_amdgcn_s_barrier()

#define STG_A(BUF, KH, KE) do { \
    async_ld16(pA[0] + (KE), &lds[(BUF)*32768 + (KH)*16384 + dstW]); \
    async_ld16(pA[1] + (KE), &lds[(BUF)*32768 + (KH)*16384 + 8192 + dstW]); \
} while (0)
#define STG_B(BUF, KH, KE) do { \
    async_ld16(pB[0] + (KE), &lds[65536 + (BUF)*32768 + (KH)*16384 + dstW]); \
    async_ld16(pB[1] + (KE), &lds[65536 + (BUF)*32768 + (KH)*16384 + 8192 + dstW]); \
} while (0)

#define RD_A(BUF, KH, MH) do { \
    const unsigned rbA_ = (BUF)*32768u + (KH)*16384u; \
    aF[0][0] = lds_read_b128(aRd[(MH)*2+0][0] + rbA_); \
    aF[0][1] = lds_read_b128(aRd[(MH)*2+0][1] + rbA_); \
    aF[1][0] = lds_read_b128(aRd[(MH)*2+1][0] + rbA_); \
    aF[1][1] = lds_read_b128(aRd[(MH)*2+1][1] + rbA_); \
} while (0)
#define RD_B(BUF, KH) do { \
    const unsigned rbB_ = (BUF)*32768u + (KH)*16384u; \
    bF[0][0] = lds_read_b128(bRd[0][0] + rbB_); \
    bF[0][1] = lds_read_b128(bRd[0][1] + rbB_); \
    bF[1][0] = lds_read_b128(bRd[1][0] + rbB_); \
    bF[1][1] = lds_read_b128(bRd[1][1] + rbB_); \
} while (0)
#define MM(MH) do { \
    _Pragma("unroll") \
    for (int ks_ = 0; ks_ < 2; ++ks_) \
      _Pragma("unroll") \
      for (int af_ = 0; af_ < 2; ++af_) \
        _Pragma("unroll") \
        for (int nf_ = 0; nf_ < 2; ++nf_) \
          acc[(MH)*2+af_][nf_] = __builtin_amdgcn_mfma_f32_32x32x16_bf16( \
              aF[af_][ks_], bF[nf_][ks_], acc[(MH)*2+af_][nf_], 0, 0, 0); \
} while (0)

template<bool SIG>
__global__ __launch_bounds__(512, 2) void gemm8p(
    const unsigned short* __restrict__ A0, const unsigned short* __restrict__ A1,
    const unsigned short* __restrict__ A2,
    const unsigned short* __restrict__ W0, const unsigned short* __restrict__ W1,
    const unsigned short* __restrict__ W2,
    const float* __restrict__ b0, const float* __restrict__ b1, const float* __restrict__ b2,
    void* __restrict__ C0, void* __restrict__ C1, void* __restrict__ C2)
{
    const int z = blockIdx.z;
    const unsigned short* A = (z == 0) ? A0 : (z == 1) ? A1 : A2;
    const unsigned short* W = (z == 0) ? W0 : (z == 1) ? W1 : W2;
    const float* bias = (z == 0) ? b0 : (z == 1) ? b1 : b2;
    void* Cp = (z == 0) ? C0 : (z == 1) ? C1 : C2;

    const int t = threadIdx.x;
    const int w = t >> 6, l = t & 63;
    const int wy = w >> 2, wx = w & 3;              // 2M x 4N waves
    const int l31 = l & 31, h5 = l >> 5;
    const int blockM = blockIdx.x * 256;
    const int blockN = blockIdx.y * 256;

    __shared__ __align__(16) unsigned char lds[131072];

    // -- ds_read absolute addresses (in-region; region addend per phase) --
    const unsigned ldsBase = (unsigned)(size_t)&lds[0];
    const int swz = (l31 >> 1) & 3;
    unsigned aRd[4][2], bRd[2][2];
    #pragma unroll
    for (int mf = 0; mf < 4; ++mf)
        #pragma unroll
        for (int ks = 0; ks < 2; ++ks)
            aRd[mf][ks] = ldsBase + (unsigned)((wy * 128 + mf * 32 + l31) * 64)
                          + (unsigned)((((ks * 2 + h5) ^ swz)) * 16);
    #pragma unroll
    for (int nf = 0; nf < 2; ++nf)
        #pragma unroll
        for (int ks = 0; ks < 2; ++ks)
            bRd[nf][ks] = ldsBase + 65536u + (unsigned)((wx * 64 + nf * 32 + l31) * 64)
                          + (unsigned)((((ks * 2 + h5) ^ swz)) * 16);

    // -- stage source pointers (inverse-swizzled global addresses) --
    const unsigned short* pA[2];
    const unsigned short* pB[2];
    #pragma unroll
    for (int i = 0; i < 2; ++i) {
        const int q = i * 512 + t;
        const int r = q >> 2;
        const int g = (q & 3) ^ ((r >> 1) & 3);
        pA[i] = A + (size_t)(blockM + r) * 1024 + g * 8;
        pB[i] = W + (size_t)(blockN + r) * 1024 + g * 8;
    }
    const int dstW = w * 1024;   // wave-uniform byte offset within region

    short8 aF[2][2], bF[2][2];
    floatx16 acc[4][2] = {};

    // -- prologue: tile0 (buf0) + tile1 (buf1) minus (1).A.kh1 --
    STG_B(0, 0, 0);  STG_A(0, 0, 0);
    STG_B(0, 1, 32); STG_A(0, 1, 32);
    STG_B(1, 0, 64); STG_A(1, 0, 64);
    STG_B(1, 1, 96);
    VMW10;            // retire (0).B.kh0 + (0).A.kh0
    BARRIER;

    #pragma unroll 1
    for (int i = 0; i < 7; ++i) {
        const int kb = i * 128;
        RD_A(0,0,0); RD_B(0,0); STG_A(1,1, kb +  96); LGKM0; MM(0);        BARRIER; // ph1
        RD_A(0,0,1);            STG_B(0,0, kb + 128); LGKM0; MM(1); VMW10; BARRIER; // ph2
        RD_A(0,1,0); RD_B(0,1); STG_A(0,0, kb + 128); LGKM0; MM(0);        BARRIER; // ph3
        RD_A(0,1,1);            STG_B(0,1, kb + 160); LGKM0; MM(1); VMW10; BARRIER; // ph4
        RD_A(1,0,0); RD_B(1,0); STG_A(0,1, kb + 160); LGKM0; MM(0);        BARRIER; // ph5
        RD_A(1,0,1);            STG_B(1,0, kb + 192); LGKM0; MM(1); VMW10; BARRIER; // ph6
        RD_A(1,1,0); RD_B(1,1); STG_A(1,0, kb + 192); LGKM0; MM(0);        BARRIER; // ph7
        RD_A(1,1,1);            STG_B(1,1, kb + 224); LGKM0; MM(1); VMW10; BARRIER; // ph8
    }
    // -- tail (tiles 14,15; stage only (15).A.kh1; drain 8/4/0) --
    RD_A(0,0,0); RD_B(0,0); STG_A(1,1, 992); LGKM0; MM(0);        BARRIER;
    RD_A(0,0,1);                             LGKM0; MM(1); VMW8;  BARRIER;
    RD_A(0,1,0); RD_B(0,1);                  LGKM0; MM(0);        BARRIER;
    RD_A(0,1,1);                             LGKM0; MM(1); VMW4;  BARRIER;
    RD_A(1,0,0); RD_B(1,0);                  LGKM0; MM(0);        BARRIER;
    RD_A(1,0,1);                             LGKM0; MM(1); VMW0;  BARRIER;
    RD_A(1,1,0); RD_B(1,1);                  LGKM0; MM(0);        BARRIER;
    RD_A(1,1,1);                             LGKM0; MM(1);

    // -- epilogue (geometry harness-verified in round 2) --
    const int colBase = blockN + wx * 64 + l31;
    const float bv0 = bias[colBase];
    const float bv1 = bias[colBase + 32];
    #pragma unroll
    for (int mf = 0; mf < 4; ++mf) {
        const int row0 = blockM + wy * 128 + mf * 32 + h5 * 4;
        #pragma unroll
        for (int nf = 0; nf < 2; ++nf) {
            const float bb = nf ? bv1 : bv0;
            const int col = colBase + nf * 32;
            #pragma unroll
            for (int rg = 0; rg < 16; ++rg) {
                const int row = row0 + (rg & 3) + 8 * (rg >> 2);
                float v = acc[mf][nf][rg] + bb;
                if (SIG) {
                    v = 1.0f / (1.0f + __expf(-v));
                    ((float*)Cp)[(size_t)row * 1024 + col] = v;
                } else {
                    ((unsigned short*)Cp)[(size_t)row * 1024 + col] = f2bf(v);
                }
            }
        }
    }
}

// ---------------------------------------------------------------------------
// MFMA attention. grid = (S=1024, 2 p-halves), block = 512 (wave = b).
// (unchanged — see earlier round comments)
// ---------------------------------------------------------------------------
__global__ __launch_bounds__(512) void attn_mfma(
    const unsigned short* __restrict__ Q,
    const unsigned short* __restrict__ Kt,
    const unsigned short* __restrict__ Vt,
    unsigned short* __restrict__ O2)
{
    constexpr int VOFF = 0;        // shorts
    constexpr int UOFF = 9216;     // shorts (16B-aligned: 18432 B)
    constexpr int QOFF = UOFF + 8192;
    __shared__ __align__(16) unsigned short lds[UOFF + 18432];

    const int s  = blockIdx.x;
    const int ph = blockIdx.y;
    const int t  = threadIdx.x;
    const int w  = t >> 6;          // wave = b
    const int l  = t & 63;
    const int l15 = l & 15, l31 = l & 31, half = l >> 5, quad = l >> 4;

    const size_t gb = ((size_t)w * 1024 + s) * 1024;  // shorts

    // ---- load phase ----
    {
        const unsigned* vg = (const unsigned*)(Vt + gb);
        unsigned* vd = (unsigned*)lds;            // Vt dword base
        #pragma unroll
        for (int it = 0; it < 8; ++it) {
            const int h = it * 2 + half;
            vd[w * 576 + h * 36 + l31] = vg[h * 32 + l31];
        }
        const unsigned short* kg = Kt + gb;
        unsigned* kd = (unsigned*)(lds + UOFF);
        #pragma unroll
        for (int h2 = 0; h2 < 8; ++h2) {
            unsigned klo = kg[(2 * h2) * 64 + l];
            unsigned khi = kg[(2 * h2 + 1) * 64 + l];
            kd[w * 512 + l * 8 + h2] = klo | (khi << 16);
        }
        const unsigned short* qg = Q + gb + ph * 32;
        unsigned* qd = (unsigned*)(lds + QOFF);
        #pragma unroll
        for (int it = 0; it < 4; ++it) {
            const int h = it * 4 + half * 2;
            unsigned qlo = qg[h * 64 + l31];
            unsigned qhi = qg[(h + 1) * 64 + l31];
            qd[w * 256 + l31 * 8 + it * 2 + half] = qlo | (qhi << 16);
        }
    }
    __syncthreads();

    // ---- scores: A=K (m=q), B=Q (n=p), K=16=h ----
    floatx16 sc[2];
    {
        short8 qf = *(const short8*)&lds[QOFF + w * 512 + l31 * 16 + half * 8];
        short8 kf0 = *(const short8*)&lds[UOFF + w * 1024 + l31 * 16 + half * 8];
        short8 kf1 = *(const short8*)&lds[UOFF + w * 1024 + (32 + l31) * 16 + half * 8];
        floatx16 z = {};
        sc[0] = __builtin_amdgcn_mfma_f32_32x32x16_bf16(kf0, qf, z, 0, 0, 0);
        sc[1] = __builtin_amdgcn_mfma_f32_32x32x16_bf16(kf1, qf, z, 0, 0, 0);
    }
    __syncthreads();   // K/Q region dead -> reuse as Sexp

    // ---- exp + Sexp[p][q] writes (p = l31, q from C layout) ----
    {
        unsigned short* sx = lds + UOFF + w * 2304 + l31 * 72;
        #pragma unroll
        for (int nt = 0; nt < 2; ++nt) {
            #pragma unroll
            for (int rg = 0; rg < 4; ++rg) {
                float e0 = __expf(sc[nt][4 * rg + 0] * 0.125f);
                float e1 = __expf(sc[nt][4 * rg + 1] * 0.125f);
                float e2 = __expf(sc[nt][4 * rg + 2] * 0.125f);
                float e3 = __expf(sc[nt][4 * rg + 3] * 0.125f);
                uint2 pk = { pack_trunc(e0, e1), pack_trunc(e2, e3) };
                const int q0 = nt * 32 + rg * 8 + half * 4;
                *(uint2*)&sx[q0] = pk;
            }
        }
    }
    __syncthreads();

    // ---- batch-softmax denominators: thread owns (p=t&31, q0=(t>>5)*4) ----
    {
        const int p  = t & 31;
        const int q0 = (t >> 5) * 4;
        unsigned short* base = lds + UOFF + p * 72 + q0;
        float fv[8][4];
        float den0 = 0.f, den1 = 0.f, den2 = 0.f, den3 = 0.f;
        #pragma unroll
        for (int b = 0; b < 8; ++b) {
            uint2 v = *(const uint2*)&base[b * 2304];
            fv[b][0] = bf2f((unsigned short)(v.x & 0xffff));
            fv[b][1] = bf2f((unsigned short)(v.x >> 16));
            fv[b][2] = bf2f((unsigned short)(v.y & 0xffff));
            fv[b][3] = bf2f((unsigned short)(v.y >> 16));
            den0 += fv[b][0]; den1 += fv[b][1]; den2 += fv[b][2]; den3 += fv[b][3];
        }
        const float r0 = __builtin_amdgcn_rcpf(den0);
        const float r1 = __builtin_amdgcn_rcpf(den1);
        const float r2 = __builtin_amdgcn_rcpf(den2);
        const float r3 = __builtin_amdgcn_rcpf(den3);
        #pragma unroll
        for (int b = 0; b < 8; ++b) {
            uint2 pk = { pack_trunc(fv[b][0] * r0, fv[b][1] * r1),
                         pack_trunc(fv[b][2] * r2, fv[b][3] * r3) };
            *(uint2*)&base[b * 2304] = pk;
        }
    }
    __syncthreads();

    // ---- PV: A=weights[p][q], B=Vt[h][q]; out[p][h] ----
    floatx4 o[2] = {};
    #pragma unroll
    for (int qc = 0; qc < 2; ++qc) {
        short8 vf = *(const short8*)&lds[VOFF + w * 1152 + l15 * 72 + qc * 32 + quad * 8];
        #pragma unroll
        for (int mt = 0; mt < 2; ++mt) {
            short8 wf = *(const short8*)&lds[UOFF + w * 2304 + (mt * 16 + l15) * 72 + qc * 32 + quad * 8];
            o[mt] = __builtin_amdgcn_mfma_f32_16x16x32_bf16(wf, vf, o[mt], 0, 0, 0);
        }
    }
    {
        unsigned short* ol = lds + UOFF + w * 2304 + l15 * 36;
        #pragma unroll
        for (int mt = 0; mt < 2; ++mt) {
            uint2 pk = { pack_trunc(o[mt][0], o[mt][1]), pack_trunc(o[mt][2], o[mt][3]) };
            *(uint2*)&ol[mt * 16 + quad * 4] = pk;
        }
    }
    __syncthreads();

    // ---- coalesced store: per wave (b), 256 dwords ----
    {
        unsigned* outdw = (unsigned*)O2;
        const unsigned* ol = (const unsigned*)(lds + UOFF + w * 2304);
        const size_t gdw = ((size_t)w * 1024 + s) * 512 + ph * 16;
        #pragma unroll
        for (int i = 0; i < 4; ++i) {
            const int d = i * 64 + l;
            const int h = d >> 4, pq = d & 15;
            outdw[gdw + h * 32 + pq] = ol[h * 18 + pq];
        }
    }
}

// ---------------------------------------------------------------------------
extern "C" void kernel_launch(void* const* d_in, const int* in_sizes, int n_in,
                              void* d_out, int out_size, void* d_ws, size_t ws_size,
                              hipStream_t stream) {
    const float* query = (const float*)d_in[0];
    const float* key_  = (const float*)d_in[1];
    const float* value = (const float*)d_in[2];
    const float* Wq = (const float*)d_in[3];
    const float* bq = (const float*)d_in[4];
    const float* Wk = (const float*)d_in[5];
    const float* bk = (const float*)d_in[6];
    const float* Wv = (const float*)d_in[7];
    const float* bv = (const float*)d_in[8];
    const float* Wo = (const float*)d_in[9];
    const float* bo = (const float*)d_in[10];

    const size_t WN = (size_t)1024 * 1024;
    const size_t MN = (size_t)8192 * 1024;

    unsigned short* Wbf = (unsigned short*)d_ws;
    unsigned short* Wq_bf = Wbf;
    unsigned short* Wk_bf = Wbf + WN;
    unsigned short* Wv_bf = Wbf + 2 * WN;
    unsigned short* Wo_bf = Wbf + 3 * WN;

    convert_weights<<<dim3(512, 4), dim3(256), 0, stream>>>(Wq, Wk, Wv, Wo, Wbf);

    const bool big = ws_size >= (4 * WN + 6 * MN) * sizeof(unsigned short); // 104 MB

    unsigned short* Qb; unsigned short* Kb; unsigned short* Vb;
    if (big) {
        unsigned short* abf = Wbf + 4 * WN;
        Qb = abf + 3 * MN; Kb = Qb + MN; Vb = Kb + MN;
        convert_acts<<<dim3(4096, 3), dim3(256), 0, stream>>>(query, key_, value, abf);
        gemm8p<false><<<dim3(32, 4, 3), dim3(512), 0, stream>>>(
            abf, abf + MN, abf + 2 * MN, Wq_bf, Wk_bf, Wv_bf, bq, bk, bv, Qb, Kb, Vb);
    } else {
        Qb = Wbf + 4 * WN; Kb = Qb + MN; Vb = Kb + MN;
        gemm128<true, false><<<dim3(64, 8, 3), dim3(256), 0, stream>>>(
            query, key_, value, Wq_bf, Wk_bf, Wv_bf, bq, bk, bv, Qb, Kb, Vb);
    }

    unsigned short* O2 = Qb;   // alias (safe, see attn_mfma)
    attn_mfma<<<dim3(1024, 2), dim3(512), 0, stream>>>(Qb, Kb, Vb, O2);

    gemm8p<true><<<dim3(32, 4, 1), dim3(512), 0, stream>>>(
        O2, O2, O2, Wo_bf, Wo_bf, Wo_bf, bo, bo, bo, d_out, d_out, d_out);
}

// Round 7
// 272.286 us; speedup vs baseline: 1.1828x; 1.0341x over previous
//
#include <hip/hip_runtime.h>

// B=8, S=1024, D=1024, H=16, P=64. FP32 I/O, bf16 MFMA compute.
// convert W+acts -> bf16 | 8-phase pipelined 256x256 QKV GEMM | MFMA
// batch-softmax attention | 4-phase 128x256 final GEMM + sigmoid (256 blocks).
// (Resubmission of round 6 — harness container failure, kernel re-audited:
// uniform control flow, in-bounds LDS/global, region ledger verified.)

using short8   = __attribute__((ext_vector_type(8))) short;    // 8 bf16
using floatx4  = __attribute__((ext_vector_type(4))) float;    // MFMA acc 16x16
using floatx16 = __attribute__((ext_vector_type(16))) float;   // MFMA acc 32x32

__device__ __forceinline__ float bf2f(unsigned short u) {
    return __uint_as_float(((unsigned)u) << 16);
}
__device__ __forceinline__ unsigned short f2bf(float f) {   // RNE
    unsigned u = __float_as_uint(f);
    u += 0x7fffu + ((u >> 16) & 1u);
    return (unsigned short)(u >> 16);
}
__device__ __forceinline__ unsigned pack_trunc(float f0, float f1) {
    return __builtin_amdgcn_perm(__float_as_uint(f1), __float_as_uint(f0), 0x07060302u);
}
__device__ __forceinline__ unsigned pack_rne(float f0, float f1) {
    return (unsigned)f2bf(f0) | ((unsigned)f2bf(f1) << 16);
}
__device__ __forceinline__ void async_ld16(const void* g, void* l) {
    __builtin_amdgcn_global_load_lds(
        (const __attribute__((address_space(1))) unsigned int*)g,
        (__attribute__((address_space(3))) unsigned int*)l, 16, 0, 0);
}
// Inline-asm LDS read: opaque to the compiler's waitcnt pass (no forced
// vmcnt(0) drain vs in-flight global_load_lds). Ordering is manual.
__device__ __forceinline__ short8 lds_read_b128(unsigned addr) {
    short8 r;
    asm volatile("ds_read_b128 %0, %1" : "=v"(r) : "v"(addr));
    return r;
}

// ---------------------------------------------------------------------------
// fp32 -> bf16 (RNE) converters
// ---------------------------------------------------------------------------
__device__ __forceinline__ void conv8(const float* src, unsigned short* d, size_t i) {
    float4 a = *(const float4*)(src + i);
    float4 b = *(const float4*)(src + i + 4);
    uint4 o;
    o.x = pack_rne(a.x, a.y);
    o.y = pack_rne(a.z, a.w);
    o.z = pack_rne(b.x, b.y);
    o.w = pack_rne(b.z, b.w);
    *(uint4*)(d + i) = o;
}

__global__ __launch_bounds__(256) void convert_weights(
    const float* __restrict__ w0, const float* __restrict__ w1,
    const float* __restrict__ w2, const float* __restrict__ w3,
    unsigned short* __restrict__ dst)
{
    const float* srcs[4] = {w0, w1, w2, w3};
    conv8(srcs[blockIdx.y], dst + (size_t)blockIdx.y * (1024u * 1024u),
          ((size_t)blockIdx.x * 256 + threadIdx.x) * 8);
}

__global__ __launch_bounds__(256) void convert_acts(
    const float* __restrict__ a0, const float* __restrict__ a1,
    const float* __restrict__ a2, unsigned short* __restrict__ dst)
{
    const float* srcs[3] = {a0, a1, a2};
    conv8(srcs[blockIdx.y], dst + (size_t)blockIdx.y * ((size_t)8192 * 1024),
          ((size_t)blockIdx.x * 256 + threadIdx.x) * 8);
}

// ---------------------------------------------------------------------------
// 128x128 GEMM (m97 structure) — small-workspace fallback only.
// ---------------------------------------------------------------------------
template<bool AF32, bool SIG>
__global__ __launch_bounds__(256) void gemm128(
    const void* __restrict__ A0, const void* __restrict__ A1, const void* __restrict__ A2,
    const unsigned short* __restrict__ W0, const unsigned short* __restrict__ W1,
    const unsigned short* __restrict__ W2,
    const float* __restrict__ b0, const float* __restrict__ b1, const float* __restrict__ b2,
    void* __restrict__ C0, void* __restrict__ C1, void* __restrict__ C2)
{
    const int z = blockIdx.z;
    const void* Ap = (z == 0) ? A0 : (z == 1) ? A1 : A2;
    const unsigned short* W = (z == 0) ? W0 : (z == 1) ? W1 : W2;
    const float* bias = (z == 0) ? b0 : (z == 1) ? b1 : b2;
    void* Cp = (z == 0) ? C0 : (z == 1) ? C1 : C2;

    constexpr int Kd = 1024, Nd = 1024;
    const int t = threadIdx.x;
    const int w = t >> 6, lane = t & 63;
    const int l15 = lane & 15, quad = lane >> 4;
    const int blockM = blockIdx.x * 128;
    const int blockN = blockIdx.y * 128;
    const int wy = w >> 1, wx = w & 1;

    __shared__ unsigned short Bs[128 * 32];
    constexpr int ABYTES = AF32 ? (128 * 32 * 4) : (128 * 32 * 2);
    __shared__ __align__(16) unsigned char AsRaw[ABYTES];
    float* AsF = (float*)AsRaw;
    unsigned short* AsB = (unsigned short*)AsRaw;

    const int br  = lane >> 2;
    const int bg  = (lane & 3) ^ (br & 3);
    const unsigned short* Bsrc0 = W + (size_t)(blockN + w * 32 + br) * Kd + bg * 8;
    const unsigned short* Bsrc1 = Bsrc0 + (size_t)16 * Kd;
    unsigned short* Bdst0 = &Bs[(w * 2 + 0) * 512];
    unsigned short* Bdst1 = &Bs[(w * 2 + 1) * 512];

    const int ar = lane >> 3;
    const int ag = (lane & 7) ^ (ar & 7);
    const float* AsrcF[4];
    float* AdstF[4];
    const unsigned short* AsrcB0 = nullptr; const unsigned short* AsrcB1 = nullptr;
    unsigned short* AdstB0 = nullptr; unsigned short* AdstB1 = nullptr;
    if (AF32) {
        #pragma unroll
        for (int j = 0; j < 4; ++j) {
            AsrcF[j] = (const float*)Ap + (size_t)(blockM + w * 32 + j * 8 + ar) * Kd + ag * 4;
            AdstF[j] = AsF + (w * 4 + j) * 256;
        }
    } else {
        AsrcB0 = (const unsigned short*)Ap + (size_t)(blockM + w * 32 + br) * Kd + bg * 8;
        AsrcB1 = AsrcB0 + (size_t)16 * Kd;
        AdstB0 = &AsB[(w * 2 + 0) * 512];
        AdstB1 = &AsB[(w * 2 + 1) * 512];
    }

    floatx4 acc[4][4] = {};

    for (int k0 = 0; k0 < Kd; k0 += 32) {
        if (AF32) {
            #pragma unroll
            for (int j = 0; j < 4; ++j) async_ld16(AsrcF[j] + k0, AdstF[j]);
        } else {
            async_ld16(AsrcB0 + k0, AdstB0);
            async_ld16(AsrcB1 + k0, AdstB1);
        }
        async_ld16(Bsrc0 + k0, Bdst0);
        async_ld16(Bsrc1 + k0, Bdst1);
        __syncthreads();

        short8 af[4], bfr[4];
        #pragma unroll
        for (int mt = 0; mt < 4; ++mt) {
            const int row = wy * 64 + mt * 16 + l15;
            if (AF32) {
                const int r7 = l15 & 7;
                const float* ap = AsF + row * 32;
                float4 lo = *(const float4*)(ap + (((quad * 2 + 0) ^ r7) * 4));
                float4 hi = *(const float4*)(ap + (((quad * 2 + 1) ^ r7) * 4));
                union { unsigned u[4]; short8 s; } cv;
                cv.u[0] = pack_rne(lo.x, lo.y);
                cv.u[1] = pack_rne(lo.z, lo.w);
                cv.u[2] = pack_rne(hi.x, hi.y);
                cv.u[3] = pack_rne(hi.z, hi.w);
                af[mt] = cv.s;
            } else {
                af[mt] = *(const short8*)&AsB[row * 32 + (quad ^ (l15 & 3)) * 8];
            }
        }
        #pragma unroll
        for (int nt = 0; nt < 4; ++nt) {
            const int row = wx * 64 + nt * 16 + l15;
            bfr[nt] = *(const short8*)&Bs[row * 32 + (quad ^ (l15 & 3)) * 8];
        }
        #pragma unroll
        for (int mt = 0; mt < 4; ++mt)
            #pragma unroll
            for (int nt = 0; nt < 4; ++nt)
                acc[mt][nt] = __builtin_amdgcn_mfma_f32_16x16x32_bf16(af[mt], bfr[nt], acc[mt][nt], 0, 0, 0);
        __syncthreads();
    }

    #pragma unroll
    for (int nt = 0; nt < 4; ++nt) {
        const int col = blockN + wx * 64 + nt * 16 + l15;
        const float bv = bias[col];
        #pragma unroll
        for (int mt = 0; mt < 4; ++mt) {
            const int row = blockM + wy * 64 + mt * 16 + quad * 4;
            #pragma unroll
            for (int r = 0; r < 4; ++r) {
                float v = acc[mt][nt][r] + bv;
                if (SIG) {
                    v = 1.0f / (1.0f + __expf(-v));
                    ((float*)Cp)[(size_t)(row + r) * Nd + col] = v;
                } else {
                    ((unsigned short*)Cp)[(size_t)(row + r) * Nd + col] = f2bf(v);
                }
            }
        }
    }
}

// ---------------------------------------------------------------------------
// gemm8p: 8-phase pipelined 256x256 GEMM (harness-verified in round 5;
// 64.3 us / 801 TF on the QKV shape). See round-5 comments for the ledger.
// ---------------------------------------------------------------------------
#define VMW10 do { asm volatile("s_waitcnt vmcnt(10)" ::: "memory"); } while (0)
#define VMW8  do { asm volatile("s_waitcnt vmcnt(8)"  ::: "memory"); } while (0)
#define VMW6  do { asm volatile("s_waitcnt vmcnt(6)"  ::: "memory"); } while (0)
#define VMW4  do { asm volatile("s_waitcnt vmcnt(4)"  ::: "memory"); } while (0)
#define VMW3  do { asm volatile("s_waitcnt vmcnt(3)"  ::: "memory"); } while (0)
#define VMW0  do { asm volatile("s_waitcnt vmcnt(0)"  ::: "memory"); } while (0)
#define LGKM0 do { asm volatile("s_waitcnt lgkmcnt(0)" ::: "memory"); \
                   __builtin_amdgcn_sched_barrier(0); } while (0)
#define BARRIER __builtin_amdgcn_s_barrier()

#define STG_A(BUF, KH, KE) do { \
    async_ld16(pA[0] + (KE), &lds[(BUF)*32768 + (KH)*16384 + dstW]); \
    async_ld16(pA[1] + (KE), &lds[(BUF)*32768 + (KH)*16384 + 8192 + dstW]); \
} while (0)
#define STG_B(BUF, KH, KE) do { \
    async_ld16(pB[0] + (KE), &lds[65536 + (BUF)*32768 + (KH)*16384 + dstW]); \
    async_ld16(pB[1] + (KE), &lds[65536 + (BUF)*32768 + (KH)*16384 + 8192 + dstW]); \
} while (0)

#define RD_A(BUF, KH, MH) do { \
    const unsigned rbA_ = (BUF)*32768u + (KH)*16384u; \
    aF[0][0] = lds_read_b128(aRd[(MH)*2+0][0] + rbA_); \
    aF[0][1] = lds_read_b128(aRd[(MH)*2+0][1] + rbA_); \
    aF[1][0] = lds_read_b128(aRd[(MH)*2+1][0] + rbA_); \
    aF[1][1] = lds_read_b128(aRd[(MH)*2+1][1] + rbA_); \
} while (0)
#define RD_B(BUF, KH) do { \
    const unsigned rbB_ = (BUF)*32768u + (KH)*16384u; \
    bF[0][0] = lds_read_b128(bRd[0][0] + rbB_); \
    bF[0][1] = lds_read_b128(bRd[0][1] + rbB_); \
    bF[1][0] = lds_read_b128(bRd[1][0] + rbB_); \
    bF[1][1] = lds_read_b128(bRd[1][1] + rbB_); \
} while (0)
#define MM(MH) do { \
    _Pragma("unroll") \
    for (int ks_ = 0; ks_ < 2; ++ks_) \
      _Pragma("unroll") \
      for (int af_ = 0; af_ < 2; ++af_) \
        _Pragma("unroll") \
        for (int nf_ = 0; nf_ < 2; ++nf_) \
          acc[(MH)*2+af_][nf_] = __builtin_amdgcn_mfma_f32_32x32x16_bf16( \
              aF[af_][ks_], bF[nf_][ks_], acc[(MH)*2+af_][nf_], 0, 0, 0); \
} while (0)

template<bool SIG>
__global__ __launch_bounds__(512, 2) void gemm8p(
    const unsigned short* __restrict__ A0, const unsigned short* __restrict__ A1,
    const unsigned short* __restrict__ A2,
    const unsigned short* __restrict__ W0, const unsigned short* __restrict__ W1,
    const unsigned short* __restrict__ W2,
    const float* __restrict__ b0, const float* __restrict__ b1, const float* __restrict__ b2,
    void* __restrict__ C0, void* __restrict__ C1, void* __restrict__ C2)
{
    const int z = blockIdx.z;
    const unsigned short* A = (z == 0) ? A0 : (z == 1) ? A1 : A2;
    const unsigned short* W = (z == 0) ? W0 : (z == 1) ? W1 : W2;
    const float* bias = (z == 0) ? b0 : (z == 1) ? b1 : b2;
    void* Cp = (z == 0) ? C0 : (z == 1) ? C1 : C2;

    const int t = threadIdx.x;
    const int w = t >> 6, l = t & 63;
    const int wy = w >> 2, wx = w & 3;              // 2M x 4N waves
    const int l31 = l & 31, h5 = l >> 5;
    const int blockM = blockIdx.x * 256;
    const int blockN = blockIdx.y * 256;

    __shared__ __align__(16) unsigned char lds[131072];

    const unsigned ldsBase = (unsigned)(size_t)&lds[0];
    const int swz = (l31 >> 1) & 3;
    unsigned aRd[4][2], bRd[2][2];
    #pragma unroll
    for (int mf = 0; mf < 4; ++mf)
        #pragma unroll
        for (int ks = 0; ks < 2; ++ks)
            aRd[mf][ks] = ldsBase + (unsigned)((wy * 128 + mf * 32 + l31) * 64)
                          + (unsigned)((((ks * 2 + h5) ^ swz)) * 16);
    #pragma unroll
    for (int nf = 0; nf < 2; ++nf)
        #pragma unroll
        for (int ks = 0; ks < 2; ++ks)
            bRd[nf][ks] = ldsBase + 65536u + (unsigned)((wx * 64 + nf * 32 + l31) * 64)
                          + (unsigned)((((ks * 2 + h5) ^ swz)) * 16);

    const unsigned short* pA[2];
    const unsigned short* pB[2];
    #pragma unroll
    for (int i = 0; i < 2; ++i) {
        const int q = i * 512 + t;
        const int r = q >> 2;
        const int g = (q & 3) ^ ((r >> 1) & 3);
        pA[i] = A + (size_t)(blockM + r) * 1024 + g * 8;
        pB[i] = W + (size_t)(blockN + r) * 1024 + g * 8;
    }
    const int dstW = w * 1024;

    short8 aF[2][2], bF[2][2];
    floatx16 acc[4][2] = {};

    STG_B(0, 0, 0);  STG_A(0, 0, 0);
    STG_B(0, 1, 32); STG_A(0, 1, 32);
    STG_B(1, 0, 64); STG_A(1, 0, 64);
    STG_B(1, 1, 96);
    VMW10;
    BARRIER;

    #pragma unroll 1
    for (int i = 0; i < 7; ++i) {
        const int kb = i * 128;
        RD_A(0,0,0); RD_B(0,0); STG_A(1,1, kb +  96); LGKM0; MM(0);        BARRIER; // ph1
        RD_A(0,0,1);            STG_B(0,0, kb + 128); LGKM0; MM(1); VMW10; BARRIER; // ph2
        RD_A(0,1,0); RD_B(0,1); STG_A(0,0, kb + 128); LGKM0; MM(0);        BARRIER; // ph3
        RD_A(0,1,1);            STG_B(0,1, kb + 160); LGKM0; MM(1); VMW10; BARRIER; // ph4
        RD_A(1,0,0); RD_B(1,0); STG_A(0,1, kb + 160); LGKM0; MM(0);        BARRIER; // ph5
        RD_A(1,0,1);            STG_B(1,0, kb + 192); LGKM0; MM(1); VMW10; BARRIER; // ph6
        RD_A(1,1,0); RD_B(1,1); STG_A(1,0, kb + 192); LGKM0; MM(0);        BARRIER; // ph7
        RD_A(1,1,1);            STG_B(1,1, kb + 224); LGKM0; MM(1); VMW10; BARRIER; // ph8
    }
    RD_A(0,0,0); RD_B(0,0); STG_A(1,1, 992); LGKM0; MM(0);        BARRIER;
    RD_A(0,0,1);                             LGKM0; MM(1); VMW8;  BARRIER;
    RD_A(0,1,0); RD_B(0,1);                  LGKM0; MM(0);        BARRIER;
    RD_A(0,1,1);                             LGKM0; MM(1); VMW4;  BARRIER;
    RD_A(1,0,0); RD_B(1,0);                  LGKM0; MM(0);        BARRIER;
    RD_A(1,0,1);                             LGKM0; MM(1); VMW0;  BARRIER;
    RD_A(1,1,0); RD_B(1,1);                  LGKM0; MM(0);        BARRIER;
    RD_A(1,1,1);                             LGKM0; MM(1);

    const int colBase = blockN + wx * 64 + l31;
    const float bv0 = bias[colBase];
    const float bv1 = bias[colBase + 32];
    #pragma unroll
    for (int mf = 0; mf < 4; ++mf) {
        const int row0 = blockM + wy * 128 + mf * 32 + h5 * 4;
        #pragma unroll
        for (int nf = 0; nf < 2; ++nf) {
            const float bb = nf ? bv1 : bv0;
            const int col = colBase + nf * 32;
            #pragma unroll
            for (int rg = 0; rg < 16; ++rg) {
                const int row = row0 + (rg & 3) + 8 * (rg >> 2);
                float v = acc[mf][nf][rg] + bb;
                if (SIG) {
                    v = 1.0f / (1.0f + __expf(-v));
                    ((float*)Cp)[(size_t)row * 1024 + col] = v;
                } else {
                    ((unsigned short*)Cp)[(size_t)row * 1024 + col] = f2bf(v);
                }
            }
        }
    }
}

// ---------------------------------------------------------------------------
// gemm4p: 4-phase pipelined 128x256 GEMM for the FINAL GEMM (full-GPU grid:
// (64,4) = 256 blocks, vs gemm8p's 128). Same verified fragment geometry,
// swizzle and region discipline as gemm8p; one (buf,kh) region per phase.
//
// LDS 96 KB: A 4 regions x 8 KB @0 (BUF*16384+KH*8192); B 4 x 16 KB @32768.
// Per phase: [8 ds_read][stage 1 region-pair: 3 loads][LGKM0][8 MFMA]
//            [VMW6][BARRIER]
// Region mapping (iter i, kb=128i): ph1 rd(0,0) stg(1,1)<-kb+96;
//   ph2 rd(0,1) stg(0,0)<-kb+128; ph3 rd(1,0) stg(0,1)<-kb+160;
//   ph4 rd(1,1) stg(1,0)<-kb+192.
// Ledger: each region staged at the phase AFTER its read (barrier-ordered);
// read 3 phases later; VMW6 at each phase end retires exactly the next
// phase's region (9 in flight -> 6; retirement is oldest-first, verified
// order: prologue (0,0),(0,1),(1,0) then (1,1),(0,0),(0,1),(1,0),...).
// Prologue stages (0,0)k0,(0,1)k32,(1,0)k64 then VMW6. Tail (iter 7):
// ph1 stages (1,1)k992 VMW6; ph2 VMW3; ph3 VMW0; ph4 reads only.
// K coverage 0..1023 verified.
// ---------------------------------------------------------------------------
#define STG4(BUF, KH, KE) do { \
    async_ld16(pA4 + (KE), &lds[(BUF)*16384 + (KH)*8192 + dstW4]); \
    async_ld16(pB4[0] + (KE), &lds[32768 + (BUF)*32768 + (KH)*16384 + dstW4]); \
    async_ld16(pB4[1] + (KE), &lds[32768 + (BUF)*32768 + (KH)*16384 + 8192 + dstW4]); \
} while (0)

#define RD4(BUF, KH) do { \
    const unsigned ra_ = (BUF)*16384u + (KH)*8192u; \
    const unsigned rb_ = (BUF)*32768u + (KH)*16384u; \
    aF[0][0] = lds_read_b128(aRd4[0][0] + ra_); \
    aF[0][1] = lds_read_b128(aRd4[0][1] + ra_); \
    aF[1][0] = lds_read_b128(aRd4[1][0] + ra_); \
    aF[1][1] = lds_read_b128(aRd4[1][1] + ra_); \
    bF[0][0] = lds_read_b128(bRd4[0][0] + rb_); \
    bF[0][1] = lds_read_b128(bRd4[0][1] + rb_); \
    bF[1][0] = lds_read_b128(bRd4[1][0] + rb_); \
    bF[1][1] = lds_read_b128(bRd4[1][1] + rb_); \
} while (0)

#define MM4 do { \
    _Pragma("unroll") \
    for (int ks_ = 0; ks_ < 2; ++ks_) \
      _Pragma("unroll") \
      for (int mf_ = 0; mf_ < 2; ++mf_) \
        _Pragma("unroll") \
        for (int nf_ = 0; nf_ < 2; ++nf_) \
          acc[mf_][nf_] = __builtin_amdgcn_mfma_f32_32x32x16_bf16( \
              aF[mf_][ks_], bF[nf_][ks_], acc[mf_][nf_], 0, 0, 0); \
} while (0)

template<bool SIG>
__global__ __launch_bounds__(512, 2) void gemm4p(
    const unsigned short* __restrict__ A,
    const unsigned short* __restrict__ W,
    const float* __restrict__ bias,
    void* __restrict__ Cp)
{
    const int t = threadIdx.x;
    const int w = t >> 6, l = t & 63;
    const int wy = w >> 2, wx = w & 3;              // 2M x 4N waves
    const int l31 = l & 31, h5 = l >> 5;
    const int blockM = blockIdx.x * 128;
    const int blockN = blockIdx.y * 256;

    __shared__ __align__(16) unsigned char lds[98304];

    const unsigned ldsBase = (unsigned)(size_t)&lds[0];
    const int swz = (l31 >> 1) & 3;
    unsigned aRd4[2][2], bRd4[2][2];
    #pragma unroll
    for (int mf = 0; mf < 2; ++mf)
        #pragma unroll
        for (int ks = 0; ks < 2; ++ks)
            aRd4[mf][ks] = ldsBase + (unsigned)((wy * 64 + mf * 32 + l31) * 64)
                           + (unsigned)((((ks * 2 + h5) ^ swz)) * 16);
    #pragma unroll
    for (int nf = 0; nf < 2; ++nf)
        #pragma unroll
        for (int ks = 0; ks < 2; ++ks)
            bRd4[nf][ks] = ldsBase + 32768u + (unsigned)((wx * 64 + nf * 32 + l31) * 64)
                           + (unsigned)((((ks * 2 + h5) ^ swz)) * 16);

    const unsigned short* pA4;
    {
        const int r = t >> 2;
        const int g = (t & 3) ^ ((r >> 1) & 3);
        pA4 = A + (size_t)(blockM + r) * 1024 + g * 8;
    }
    const unsigned short* pB4[2];
    #pragma unroll
    for (int i = 0; i < 2; ++i) {
        const int q = i * 512 + t;
        const int r = q >> 2;
        const int g = (q & 3) ^ ((r >> 1) & 3);
        pB4[i] = W + (size_t)(blockN + r) * 1024 + g * 8;
    }
    const int dstW4 = w * 1024;

    short8 aF[2][2], bF[2][2];
    floatx16 acc[2][2] = {};

    // prologue: (0,0)<-k0, (0,1)<-k32, (1,0)<-k64; retire first region
    STG4(0, 0, 0); STG4(0, 1, 32); STG4(1, 0, 64);
    VMW6;
    BARRIER;

    #pragma unroll 1
    for (int i = 0; i < 7; ++i) {
        const int kb = i * 128;
        RD4(0,0); STG4(1,1, kb +  96); LGKM0; MM4; VMW6; BARRIER;
        RD4(0,1); STG4(0,0, kb + 128); LGKM0; MM4; VMW6; BARRIER;
        RD4(1,0); STG4(0,1, kb + 160); LGKM0; MM4; VMW6; BARRIER;
        RD4(1,1); STG4(1,0, kb + 192); LGKM0; MM4; VMW6; BARRIER;
    }
    // tail: tiles k = 896, 928, 960, 992
    RD4(0,0); STG4(1,1, 992); LGKM0; MM4; VMW6; BARRIER;
    RD4(0,1);                 LGKM0; MM4; VMW3; BARRIER;
    RD4(1,0);                 LGKM0; MM4; VMW0; BARRIER;
    RD4(1,1);                 LGKM0; MM4;

    const int colBase = blockN + wx * 64 + l31;
    const float bv0 = bias[colBase];
    const float bv1 = bias[colBase + 32];
    #pragma unroll
    for (int mf = 0; mf < 2; ++mf) {
        const int row0 = blockM + wy * 64 + mf * 32 + h5 * 4;
        #pragma unroll
        for (int nf = 0; nf < 2; ++nf) {
            const float bb = nf ? bv1 : bv0;
            const int col = colBase + nf * 32;
            #pragma unroll
            for (int rg = 0; rg < 16; ++rg) {
                const int row = row0 + (rg & 3) + 8 * (rg >> 2);
                float v = acc[mf][nf][rg] + bb;
                if (SIG) {
                    v = 1.0f / (1.0f + __expf(-v));
                    ((float*)Cp)[(size_t)row * 1024 + col] = v;
                } else {
                    ((unsigned short*)Cp)[(size_t)row * 1024 + col] = f2bf(v);
                }
            }
        }
    }
}

// ---------------------------------------------------------------------------
// MFMA attention. grid = (S=1024, 2 p-halves), block = 512 (wave = b).
// (unchanged — see earlier round comments)
// ---------------------------------------------------------------------------
__global__ __launch_bounds__(512) void attn_mfma(
    const unsigned short* __restrict__ Q,
    const unsigned short* __restrict__ Kt,
    const unsigned short* __restrict__ Vt,
    unsigned short* __restrict__ O2)
{
    constexpr int VOFF = 0;        // shorts
    constexpr int UOFF = 9216;     // shorts (16B-aligned: 18432 B)
    constexpr int QOFF = UOFF + 8192;
    __shared__ __align__(16) unsigned short lds[UOFF + 18432];

    const int s  = blockIdx.x;
    const int ph = blockIdx.y;
    const int t  = threadIdx.x;
    const int w  = t >> 6;          // wave = b
    const int l  = t & 63;
    const int l15 = l & 15, l31 = l & 31, half = l >> 5, quad = l >> 4;

    const size_t gb = ((size_t)w * 1024 + s) * 1024;  // shorts

    // ---- load phase ----
    {
        const unsigned* vg = (const unsigned*)(Vt + gb);
        unsigned* vd = (unsigned*)lds;            // Vt dword base
        #pragma unroll
        for (int it = 0; it < 8; ++it) {
            const int h = it * 2 + half;
            vd[w * 576 + h * 36 + l31] = vg[h * 32 + l31];
        }
        const unsigned short* kg = Kt + gb;
        unsigned* kd = (unsigned*)(lds + UOFF);
        #pragma unroll
        for (int h2 = 0; h2 < 8; ++h2) {
            unsigned klo = kg[(2 * h2) * 64 + l];
            unsigned khi = kg[(2 * h2 + 1) * 64 + l];
            kd[w * 512 + l * 8 + h2] = klo | (khi << 16);
        }
        const unsigned short* qg = Q + gb + ph * 32;
        unsigned* qd = (unsigned*)(lds + QOFF);
        #pragma unroll
        for (int it = 0; it < 4; ++it) {
            const int h = it * 4 + half * 2;
            unsigned qlo = qg[h * 64 + l31];
            unsigned qhi = qg[(h + 1) * 64 + l31];
            qd[w * 256 + l31 * 8 + it * 2 + half] = qlo | (qhi << 16);
        }
    }
    __syncthreads();

    // ---- scores: A=K (m=q), B=Q (n=p), K=16=h ----
    floatx16 sc[2];
    {
        short8 qf = *(const short8*)&lds[QOFF + w * 512 + l31 * 16 + half * 8];
        short8 kf0 = *(const short8*)&lds[UOFF + w * 1024 + l31 * 16 + half * 8];
        short8 kf1 = *(const short8*)&lds[UOFF + w * 1024 + (32 + l31) * 16 + half * 8];
        floatx16 z = {};
        sc[0] = __builtin_amdgcn_mfma_f32_32x32x16_bf16(kf0, qf, z, 0, 0, 0);
        sc[1] = __builtin_amdgcn_mfma_f32_32x32x16_bf16(kf1, qf, z, 0, 0, 0);
    }
    __syncthreads();   // K/Q region dead -> reuse as Sexp

    // ---- exp + Sexp[p][q] writes (p = l31, q from C layout) ----
    {
        unsigned short* sx = lds + UOFF + w * 2304 + l31 * 72;
        #pragma unroll
        for (int nt = 0; nt < 2; ++nt) {
            #pragma unroll
            for (int rg = 0; rg < 4; ++rg) {
                float e0 = __expf(sc[nt][4 * rg + 0] * 0.125f);
                float e1 = __expf(sc[nt][4 * rg + 1] * 0.125f);
                float e2 = __expf(sc[nt][4 * rg + 2] * 0.125f);
                float e3 = __expf(sc[nt][4 * rg + 3] * 0.125f);
                uint2 pk = { pack_trunc(e0, e1), pack_trunc(e2, e3) };
                const int q0 = nt * 32 + rg * 8 + half * 4;
                *(uint2*)&sx[q0] = pk;
            }
        }
    }
    __syncthreads();

    // ---- batch-softmax denominators: thread owns (p=t&31, q0=(t>>5)*4) ----
    {
        const int p  = t & 31;
        const int q0 = (t >> 5) * 4;
        unsigned short* base = lds + UOFF + p * 72 + q0;
        float fv[8][4];
        float den0 = 0.f, den1 = 0.f, den2 = 0.f, den3 = 0.f;
        #pragma unroll
        for (int b = 0; b < 8; ++b) {
            uint2 v = *(const uint2*)&base[b * 2304];
            fv[b][0] = bf2f((unsigned short)(v.x & 0xffff));
            fv[b][1] = bf2f((unsigned short)(v.x >> 16));
            fv[b][2] = bf2f((unsigned short)(v.y & 0xffff));
            fv[b][3] = bf2f((unsigned short)(v.y >> 16));
            den0 += fv[b][0]; den1 += fv[b][1]; den2 += fv[b][2]; den3 += fv[b][3];
        }
        const float r0 = __builtin_amdgcn_rcpf(den0);
        const float r1 = __builtin_amdgcn_rcpf(den1);
        const float r2 = __builtin_amdgcn_rcpf(den2);
        const float r3 = __builtin_amdgcn_rcpf(den3);
        #pragma unroll
        for (int b = 0; b < 8; ++b) {
            uint2 pk = { pack_trunc(fv[b][0] * r0, fv[b][1] * r1),
                         pack_trunc(fv[b][2] * r2, fv[b][3] * r3) };
            *(uint2*)&base[b * 2304] = pk;
        }
    }
    __syncthreads();

    // ---- PV: A=weights[p][q], B=Vt[h][q]; out[p][h] ----
    floatx4 o[2] = {};
    #pragma unroll
    for (int qc = 0; qc < 2; ++qc) {
        short8 vf = *(const short8*)&lds[VOFF + w * 1152 + l15 * 72 + qc * 32 + quad * 8];
        #pragma unroll
        for (int mt = 0; mt < 2; ++mt) {
            short8 wf = *(const short8*)&lds[UOFF + w * 2304 + (mt * 16 + l15) * 72 + qc * 32 + quad * 8];
            o[mt] = __builtin_amdgcn_mfma_f32_16x16x32_bf16(wf, vf, o[mt], 0, 0, 0);
        }
    }
    {
        unsigned short* ol = lds + UOFF + w * 2304 + l15 * 36;
        #pragma unroll
        for (int mt = 0; mt < 2; ++mt) {
            uint2 pk = { pack_trunc(o[mt][0], o[mt][1]), pack_trunc(o[mt][2], o[mt][3]) };
            *(uint2*)&ol[mt * 16 + quad * 4] = pk;
        }
    }
    __syncthreads();

    // ---- coalesced store: per wave (b), 256 dwords ----
    {
        unsigned* outdw = (unsigned*)O2;
        const unsigned* ol = (const unsigned*)(lds + UOFF + w * 2304);
        const size_t gdw = ((size_t)w * 1024 + s) * 512 + ph * 16;
        #pragma unroll
        for (int i = 0; i < 4; ++i) {
            const int d = i * 64 + l;
            const int h = d >> 4, pq = d & 15;
            outdw[gdw + h * 32 + pq] = ol[h * 18 + pq];
        }
    }
}

// ---------------------------------------------------------------------------
extern "C" void kernel_launch(void* const* d_in, const int* in_sizes, int n_in,
                              void* d_out, int out_size, void* d_ws, size_t ws_size,
                              hipStream_t stream) {
    const float* query = (const float*)d_in[0];
    const float* key_  = (const float*)d_in[1];
    const float* value = (const float*)d_in[2];
    const float* Wq = (const float*)d_in[3];
    const float* bq = (const float*)d_in[4];
    const float* Wk = (const float*)d_in[5];
    const float* bk = (const float*)d_in[6];
    const float* Wv = (const float*)d_in[7];
    const float* bv = (const float*)d_in[8];
    const float* Wo = (const float*)d_in[9];
    const float* bo = (const float*)d_in[10];

    const size_t WN = (size_t)1024 * 1024;
    const size_t MN = (size_t)8192 * 1024;

    unsigned short* Wbf = (unsigned short*)d_ws;
    unsigned short* Wq_bf = Wbf;
    unsigned short* Wk_bf = Wbf + WN;
    unsigned short* Wv_bf = Wbf + 2 * WN;
    unsigned short* Wo_bf = Wbf + 3 * WN;

    convert_weights<<<dim3(512, 4), dim3(256), 0, stream>>>(Wq, Wk, Wv, Wo, Wbf);

    const bool big = ws_size >= (4 * WN + 6 * MN) * sizeof(unsigned short); // 104 MB

    unsigned short* Qb; unsigned short* Kb; unsigned short* Vb;
    if (big) {
        unsigned short* abf = Wbf + 4 * WN;
        Qb = abf + 3 * MN; Kb = Qb + MN; Vb = Kb + MN;
        convert_acts<<<dim3(4096, 3), dim3(256), 0, stream>>>(query, key_, value, abf);
        gemm8p<false><<<dim3(32, 4, 3), dim3(512), 0, stream>>>(
            abf, abf + MN, abf + 2 * MN, Wq_bf, Wk_bf, Wv_bf, bq, bk, bv, Qb, Kb, Vb);
    } else {
        Qb = Wbf + 4 * WN; Kb = Qb + MN; Vb = Kb + MN;
        gemm128<true, false><<<dim3(64, 8, 3), dim3(256), 0, stream>>>(
            query, key_, value, Wq_bf, Wk_bf, Wv_bf, bq, bk, bv, Qb, Kb, Vb);
    }

    unsigned short* O2 = Qb;   // alias (safe, see attn_mfma)
    attn_mfma<<<dim3(1024, 2), dim3(512), 0, stream>>>(Qb, Kb, Vb, O2);

    gemm4p<true><<<dim3(64, 4), dim3(512), 0, stream>>>(O2, Wo_bf, bo, (float*)d_out);
}